// Round 4
// baseline (150.380 us; speedup 1.0000x reference)
//
#include <hip/hip_runtime.h>
#include <stdint.h>

#define C 64
#define HH 112
#define WWD 112
#define HW (HH*WWD)
#define NB 32
#define MTOT (NB*HW)
#define PPR 56          // pixel-pairs per row
#define PPI 6272        // pixel-pairs per image (HW/2)
#define PACK_BLKS 1568  // 32 images * 49 chunks of 256 pixels
#define CONV_BLKS 25    // ceil(PPI/256)

typedef unsigned long long u64t;

// ---- K1: pack sign bitplane (blocks 0..1567) + weight prep (blocks 1568..1631)
//          + zero the stats accumulators (block 1568, threads 64..255)
__global__ __launch_bounds__(256) void k_prep_pack(
        const float* __restrict__ x, const float* __restrict__ b0,
        const float* __restrict__ w,
        uint64_t* __restrict__ xp,
        uint64_t* __restrict__ wbits, float* __restrict__ wscale,
        int* __restrict__ corrP, int* __restrict__ ps, u64t* __restrict__ pq) {
    int bid = blockIdx.x;
    if (bid < PACK_BLKS) {
        int n = bid / 49;
        int pix = (bid % 49) * 256 + threadIdx.x;
        uint64_t p = 0;
        const float* xb = x + (size_t)n * C * HW + pix;
        #pragma unroll
        for (int c = 0; c < C; ++c) {
            float v = xb[(size_t)c * HW] + b0[c];
            p |= (uint64_t)(v > 0.f) << c;
        }
        xp[(size_t)n*HW + pix] = p;
    } else {
        int tid = threadIdx.x;
        int o = bid - PACK_BLKS;            // 0..63
        if (tid < 64) {
            int i = tid;                    // input channel
            const float* wp = w + ((size_t)o*C + i)*9;
            float s = 0.f;
            uint64_t b[9];
            #pragma unroll
            for (int k = 0; k < 9; ++k) {
                float v = wp[k];
                s += fabsf(v);
                b[k] = __ballot(v > 0.f);
            }
            #pragma unroll
            for (int off = 32; off > 0; off >>= 1) s += __shfl_down(s, off);
            if (i == 0) {
                wscale[o] = s * (1.0f/576.0f);
                int pq9[9];
                #pragma unroll
                for (int k = 0; k < 9; ++k) {
                    wbits[o*9+k] = b[k];
                    pq9[k] = __popcll(b[k]);
                }
                for (int rc = 0; rc < 3; ++rc)
                    for (int cc = 0; cc < 3; ++cc) {
                        int corr = 0;
                        for (int kr = 0; kr < 3; ++kr)
                            for (int kc = 0; kc < 3; ++kc) {
                                bool oob = (rc==0 && kr==0) || (rc==2 && kr==2) ||
                                           (cc==0 && kc==0) || (cc==2 && kc==2);
                                if (oob) corr += 64 - 2*pq9[kr*3+kc];
                            }
                        corrP[(rc*3+cc)*C + o] = 576 - corr;
                    }
            }
        } else if (bid == PACK_BLKS) {
            // zero stats accumulators every call (replay-deterministic atomics)
            for (int i = tid - 64; i < C*8; i += 192) { ps[i] = 0; pq[i] = 0ull; }
        }
    }
}

// ---- K2: fused conv + BN-stats. No conv store: wave butterfly -> LDS -> atomics.
__global__ __launch_bounds__(256) void k_convstats(
        const uint64_t* __restrict__ xp, const uint64_t* __restrict__ wbits,
        const int* __restrict__ corrP, int* __restrict__ ps, u64t* __restrict__ pq) {
    __shared__ uint64_t sq[C*9];
    __shared__ int scor[9*C];
    __shared__ int lsw[4][C];
    __shared__ int lqw[4][C];
    for (int i = threadIdx.x; i < C*9; i += 256) sq[i] = wbits[i];
    for (int i = threadIdx.x; i < 9*C; i += 256) scor[i] = corrP[i];
    __syncthreads();

    int n = blockIdx.y;
    int pr = blockIdx.x * 256 + threadIdx.x;
    int act = pr < PPI;
    int prc = act ? pr : (PPI - 1);
    int row = prc / PPR;
    int j   = prc - row * PPR;
    int c0  = 2 * j;
    const uint64_t* base = xp + (size_t)n * HW;
    uint64_t P[12];
    #pragma unroll
    for (int r = 0; r < 3; ++r) {
        int rr = row + r - 1;
        bool okr = (rr >= 0) & (rr < HH);
        #pragma unroll
        for (int c = 0; c < 4; ++c) {
            int cc = c0 + c - 1;
            bool ok = okr & (cc >= 0) & (cc < WWD);
            P[r*4+c] = ok ? base[(size_t)rr * WWD + cc] : 0ull;
        }
    }
    int rc   = (row == 0) ? 0 : ((row == HH-1) ? 2 : 1);
    int reg0 = (rc*3 + ((c0 == 0) ? 0 : 1)) * C;
    int reg1 = (rc*3 + ((c0 == WWD-2) ? 2 : 1)) * C;
    int wid = threadIdx.x >> 6, lane = threadIdx.x & 63;

    #pragma unroll 2
    for (int o = 0; o < C; ++o) {
        const uint64_t* q = &sq[o*9];
        int a0 = 0, a1 = 0;
        #pragma unroll
        for (int r = 0; r < 3; ++r) {
            #pragma unroll
            for (int c = 0; c < 3; ++c) {
                uint64_t qk = q[r*3+c];
                a0 += __popcll(P[r*4+c]   ^ qk);
                a1 += __popcll(P[r*4+c+1] ^ qk);
            }
        }
        int v0 = scor[reg0 + o] - 2*a0;
        int v1 = scor[reg1 + o] - 2*a1;
        int s = act ? (v0 + v1) : 0;
        int qq = act ? (v0*v0 + v1*v1) : 0;
        #pragma unroll
        for (int off = 1; off < 64; off <<= 1) {
            s  += __shfl_xor(s,  off);
            qq += __shfl_xor(qq, off);
        }
        if (lane == 0) { lsw[wid][o] = s; lqw[wid][o] = qq; }
    }
    __syncthreads();
    int t = threadIdx.x;
    if (t < C) {
        int st = lsw[0][t] + lsw[1][t] + lsw[2][t] + lsw[3][t];
        atomicAdd(&ps[t*8 + (n & 7)], st);
    } else if (t < 2*C) {
        int o = t - C;
        unsigned int qt = (unsigned)lqw[0][o] + (unsigned)lqw[1][o]
                        + (unsigned)lqw[2][o] + (unsigned)lqw[3][o];
        atomicAdd(&pq[o*8 + (n & 7)], (u64t)qt);
    }
}

// ---- K3: finish — recompute conv from bitplanes, BN affine from exact int sums,
//          fused BN + residual + b1 + PReLU + b2, float2 I/O.
__global__ __launch_bounds__(256) void k_finish(
        const uint64_t* __restrict__ xp, const uint64_t* __restrict__ wbits,
        const int* __restrict__ corrP, const int* __restrict__ ps,
        const u64t* __restrict__ pq, const float* __restrict__ x,
        const float* __restrict__ wscale, const float* __restrict__ gamma,
        const float* __restrict__ beta, const float* __restrict__ b1,
        const float* __restrict__ alpha, const float* __restrict__ b2,
        float* __restrict__ out) {
    __shared__ uint64_t sq[C*9];
    __shared__ int scor[9*C];
    __shared__ float4 tab[C];   // {A, B(+b1), alpha, b2}
    for (int i = threadIdx.x; i < C*9; i += 256) sq[i] = wbits[i];
    for (int i = threadIdx.x; i < 9*C; i += 256) scor[i] = corrP[i];
    if (threadIdx.x < C) {
        int o = threadIdx.x;
        int s = 0; u64t qv = 0;
        #pragma unroll
        for (int k = 0; k < 8; ++k) { s += ps[o*8+k]; qv += pq[o*8+k]; }
        const float inv = 1.0f / (float)MTOT;
        float sc   = wscale[o];
        float mean = (float)s * inv;
        float ek2  = (float)qv * inv;
        float mu   = sc * mean;
        float var  = sc*sc*ek2 - mu*mu;
        float g    = gamma[o] * rsqrtf(var + 1e-5f);
        tab[o] = make_float4(g*sc, beta[o] - g*mu + b1[o], alpha[o], b2[o]);
    }
    __syncthreads();

    int n = blockIdx.y;
    int pr = blockIdx.x * 256 + threadIdx.x;
    if (pr >= PPI) return;
    int row = pr / PPR;
    int j   = pr - row * PPR;
    int c0  = 2 * j;
    const uint64_t* base = xp + (size_t)n * HW;
    uint64_t P[12];
    #pragma unroll
    for (int r = 0; r < 3; ++r) {
        int rr = row + r - 1;
        bool okr = (rr >= 0) & (rr < HH);
        #pragma unroll
        for (int c = 0; c < 4; ++c) {
            int cc = c0 + c - 1;
            bool ok = okr & (cc >= 0) & (cc < WWD);
            P[r*4+c] = ok ? base[(size_t)rr * WWD + cc] : 0ull;
        }
    }
    int rc   = (row == 0) ? 0 : ((row == HH-1) ? 2 : 1);
    int reg0 = (rc*3 + ((c0 == 0) ? 0 : 1)) * C;
    int reg1 = (rc*3 + ((c0 == WWD-2) ? 2 : 1)) * C;

    const float2* x2 = (const float2*)x + (size_t)n * C * (HW/2) + pr;
    float2*       o2 = (float2*)out     + (size_t)n * C * (HW/2) + pr;
    for (int o = 0; o < C; ++o) {
        const uint64_t* q = &sq[o*9];
        int a0 = 0, a1 = 0;
        #pragma unroll
        for (int r = 0; r < 3; ++r) {
            #pragma unroll
            for (int c = 0; c < 3; ++c) {
                uint64_t qk = q[r*3+c];
                a0 += __popcll(P[r*4+c]   ^ qk);
                a1 += __popcll(P[r*4+c+1] ^ qk);
            }
        }
        int v0 = scor[reg0 + o] - 2*a0;
        int v1 = scor[reg1 + o] - 2*a1;
        float4 t4 = tab[o];
        float2 xv = x2[(size_t)o * (HW/2)];
        float t0 = t4.x * (float)v0 + t4.y + xv.x;
        float t1 = t4.x * (float)v1 + t4.y + xv.y;
        t0 = t0 > 0.f ? t0 : t4.z * t0;
        t1 = t1 > 0.f ? t1 : t4.z * t1;
        o2[(size_t)o * (HW/2)] = make_float2(t0 + t4.w, t1 + t4.w);
    }
}

extern "C" void kernel_launch(void* const* d_in, const int* in_sizes, int n_in,
                              void* d_out, int out_size, void* d_ws, size_t ws_size,
                              hipStream_t stream) {
    const float* x     = (const float*)d_in[0];
    const float* b0    = (const float*)d_in[1];
    const float* w     = (const float*)d_in[2];
    const float* gamma = (const float*)d_in[3];
    const float* beta  = (const float*)d_in[4];
    const float* b1    = (const float*)d_in[5];
    const float* alpha = (const float*)d_in[6];
    const float* b2    = (const float*)d_in[7];

    char* ws = (char*)d_ws;
    const size_t XPB = (size_t)NB * HW * sizeof(uint64_t);   // 3,211,264 B
    uint64_t* xp     = (uint64_t*)ws;
    uint64_t* wbits  = (uint64_t*)(ws + XPB);                // 4608 B
    u64t*     pq     = (u64t*)(ws + XPB + 4608);             // 4096 B
    float*    wscale = (float*)(ws + XPB + 4608 + 4096);     // 256 B
    int*      corrP  = (int*)(ws + XPB + 4608 + 4096 + 256); // 2304 B
    int*      ps     = (int*)(ws + XPB + 4608 + 4096 + 256 + 2304); // 2048 B

    hipLaunchKernelGGL(k_prep_pack, dim3(PACK_BLKS + 64), dim3(256), 0, stream,
                       x, b0, w, xp, wbits, wscale, corrP, ps, pq);
    hipLaunchKernelGGL(k_convstats, dim3(CONV_BLKS, NB), dim3(256), 0, stream,
                       xp, wbits, corrP, ps, pq);
    hipLaunchKernelGGL(k_finish, dim3(CONV_BLKS, NB), dim3(256), 0, stream,
                       xp, wbits, corrP, ps, pq, x, wscale, gamma, beta, b1, alpha, b2,
                       (float*)d_out);
}

// Round 5
// 126.335 us; speedup vs baseline: 1.1903x; 1.1903x over previous
//
#include <hip/hip_runtime.h>
#include <stdint.h>

#define C 64
#define HH 112
#define WWD 112
#define HW (HH*WWD)
#define NB 32
#define MTOT (NB*HW)
#define PPR 56          // pixel-pairs per row
#define PPI 6272        // pixel-pairs per image (HW/2)
#define PACK_BLKS 1568  // 32 images * 49 chunks of 256 pixels
#define CONV_BLKS 25    // ceil(PPI/256)
#define OH 32           // output channels per block (z-split in 2)

typedef unsigned long long u64t;

// ---- K1: pack sign bitplane (blocks 0..1567) + weight prep (blocks 1568..1631)
//          + zero stats accumulators (block 1568, threads 64..255)
__global__ __launch_bounds__(256) void k_prep_pack(
        const float* __restrict__ x, const float* __restrict__ b0,
        const float* __restrict__ w,
        uint64_t* __restrict__ xp,
        uint64_t* __restrict__ wbits, float* __restrict__ wscale,
        int* __restrict__ corrP, int* __restrict__ ps, u64t* __restrict__ pq) {
    int bid = blockIdx.x;
    if (bid < PACK_BLKS) {
        int n = bid / 49;
        int pix = (bid % 49) * 256 + threadIdx.x;
        uint64_t p = 0;
        const float* xb = x + (size_t)n * C * HW + pix;
        #pragma unroll
        for (int c = 0; c < C; ++c) {
            float v = xb[(size_t)c * HW] + b0[c];
            p |= (uint64_t)(v > 0.f) << c;
        }
        xp[(size_t)n*HW + pix] = p;
    } else {
        int tid = threadIdx.x;
        int o = bid - PACK_BLKS;            // 0..63
        if (tid < 64) {
            int i = tid;                    // input channel
            const float* wp = w + ((size_t)o*C + i)*9;
            float s = 0.f;
            uint64_t b[9];
            #pragma unroll
            for (int k = 0; k < 9; ++k) {
                float v = wp[k];
                s += fabsf(v);
                b[k] = __ballot(v > 0.f);
            }
            #pragma unroll
            for (int off = 32; off > 0; off >>= 1) s += __shfl_down(s, off);
            if (i == 0) {
                wscale[o] = s * (1.0f/576.0f);
                int pq9[9];
                #pragma unroll
                for (int k = 0; k < 9; ++k) {
                    wbits[o*9+k] = b[k];
                    pq9[k] = __popcll(b[k]);
                }
                for (int rc = 0; rc < 3; ++rc)
                    for (int cc = 0; cc < 3; ++cc) {
                        int corr = 0;
                        for (int kr = 0; kr < 3; ++kr)
                            for (int kc = 0; kc < 3; ++kc) {
                                bool oob = (rc==0 && kr==0) || (rc==2 && kr==2) ||
                                           (cc==0 && kc==0) || (cc==2 && kc==2);
                                if (oob) corr += 64 - 2*pq9[kr*3+kc];
                            }
                        corrP[(rc*3+cc)*C + o] = 576 - corr;
                    }
            }
        } else if (bid == PACK_BLKS) {
            for (int i = tid - 64; i < C*8; i += 192) { ps[i] = 0; pq[i] = 0ull; }
        }
    }
}

// ---- K2: conv + BN-stats only (no conv store). o-split across z (32 o / block).
__global__ __launch_bounds__(256) void k_convstats(
        const uint64_t* __restrict__ xp, const uint64_t* __restrict__ wbits,
        const int* __restrict__ corrP, int* __restrict__ ps, u64t* __restrict__ pq) {
    __shared__ uint64_t sq[OH*9];
    __shared__ int scor[9*OH];
    __shared__ int lsw[4][OH];
    __shared__ int lqw[4][OH];
    const int obase = blockIdx.z * OH;
    for (int i = threadIdx.x; i < OH*9; i += 256) sq[i] = wbits[obase*9 + i];
    for (int i = threadIdx.x; i < 9*OH; i += 256) {
        int r = i / OH, oo = i - r*OH;
        scor[i] = corrP[r*C + obase + oo];
    }
    __syncthreads();

    int n = blockIdx.y;
    int pr = blockIdx.x * 256 + threadIdx.x;
    int act = pr < PPI;
    int prc = act ? pr : (PPI - 1);
    int row = prc / PPR;
    int j   = prc - row * PPR;
    int c0  = 2 * j;
    const uint64_t* base = xp + (size_t)n * HW;
    uint64_t P[12];
    #pragma unroll
    for (int r = 0; r < 3; ++r) {
        int rr = row + r - 1;
        bool okr = (rr >= 0) & (rr < HH);
        #pragma unroll
        for (int c = 0; c < 4; ++c) {
            int cc = c0 + c - 1;
            bool ok = okr & (cc >= 0) & (cc < WWD);
            P[r*4+c] = ok ? base[(size_t)rr * WWD + cc] : 0ull;
        }
    }
    int rc   = (row == 0) ? 0 : ((row == HH-1) ? 2 : 1);
    int reg0 = (rc*3 + ((c0 == 0) ? 0 : 1)) * OH;
    int reg1 = (rc*3 + ((c0 == WWD-2) ? 2 : 1)) * OH;
    int wid = threadIdx.x >> 6, lane = threadIdx.x & 63;

    #pragma unroll 2
    for (int oo = 0; oo < OH; ++oo) {
        const uint64_t* q = &sq[oo*9];
        int a0 = 0, a1 = 0;
        #pragma unroll
        for (int r = 0; r < 3; ++r) {
            #pragma unroll
            for (int c = 0; c < 3; ++c) {
                uint64_t qk = q[r*3+c];
                a0 += __popcll(P[r*4+c]   ^ qk);
                a1 += __popcll(P[r*4+c+1] ^ qk);
            }
        }
        int v0 = scor[reg0 + oo] - 2*a0;
        int v1 = scor[reg1 + oo] - 2*a1;
        int s  = act ? (v0 + v1) : 0;
        int qq = act ? (v0*v0 + v1*v1) : 0;
        #pragma unroll
        for (int off = 1; off < 64; off <<= 1) {
            s  += __shfl_xor(s,  off);
            qq += __shfl_xor(qq, off);
        }
        if (lane == 0) { lsw[wid][oo] = s; lqw[wid][oo] = qq; }
    }
    __syncthreads();
    int t = threadIdx.x;
    int bkt = blockIdx.y & 7;
    if (t < OH) {
        int st = lsw[0][t] + lsw[1][t] + lsw[2][t] + lsw[3][t];
        atomicAdd(&ps[(obase + t)*8 + bkt], st);
    } else if (t < 2*OH) {
        int oo = t - OH;
        unsigned int qt = (unsigned)lqw[0][oo] + (unsigned)lqw[1][oo]
                        + (unsigned)lqw[2][oo] + (unsigned)lqw[3][oo];
        atomicAdd(&pq[(obase + oo)*8 + bkt], (u64t)qt);
    }
}

// ---- K3: finish — phase A: recompute conv into regs (32 o); phase B: pure stream.
__global__ __launch_bounds__(256) void k_finish(
        const uint64_t* __restrict__ xp, const uint64_t* __restrict__ wbits,
        const int* __restrict__ corrP, const int* __restrict__ ps,
        const u64t* __restrict__ pq, const float* __restrict__ x,
        const float* __restrict__ wscale, const float* __restrict__ gamma,
        const float* __restrict__ beta, const float* __restrict__ b1,
        const float* __restrict__ alpha, const float* __restrict__ b2,
        float* __restrict__ out) {
    __shared__ uint64_t sq[OH*9];
    __shared__ int scor[9*OH];
    __shared__ float4 tab[OH];   // {A, B(+b1), alpha, b2}
    const int obase = blockIdx.z * OH;
    for (int i = threadIdx.x; i < OH*9; i += 256) sq[i] = wbits[obase*9 + i];
    for (int i = threadIdx.x; i < 9*OH; i += 256) {
        int r = i / OH, oo = i - r*OH;
        scor[i] = corrP[r*C + obase + oo];
    }
    if (threadIdx.x < OH) {
        int o = obase + threadIdx.x;
        int s = 0; u64t qv = 0;
        #pragma unroll
        for (int k = 0; k < 8; ++k) { s += ps[o*8+k]; qv += pq[o*8+k]; }
        const float inv = 1.0f / (float)MTOT;
        float sc   = wscale[o];
        float mean = (float)s * inv;
        float ek2  = (float)qv * inv;
        float mu   = sc * mean;
        float var  = sc*sc*ek2 - mu*mu;
        float g    = gamma[o] * rsqrtf(var + 1e-5f);
        tab[threadIdx.x] = make_float4(g*sc, beta[o] - g*mu + b1[o], alpha[o], b2[o]);
    }
    __syncthreads();

    int n = blockIdx.y;
    int pr = blockIdx.x * 256 + threadIdx.x;
    if (pr >= PPI) return;
    int row = pr / PPR;
    int j   = pr - row * PPR;
    int c0  = 2 * j;
    const uint64_t* base = xp + (size_t)n * HW;
    uint64_t P[12];
    #pragma unroll
    for (int r = 0; r < 3; ++r) {
        int rr = row + r - 1;
        bool okr = (rr >= 0) & (rr < HH);
        #pragma unroll
        for (int c = 0; c < 4; ++c) {
            int cc = c0 + c - 1;
            bool ok = okr & (cc >= 0) & (cc < WWD);
            P[r*4+c] = ok ? base[(size_t)rr * WWD + cc] : 0ull;
        }
    }
    int rc   = (row == 0) ? 0 : ((row == HH-1) ? 2 : 1);
    int reg0 = (rc*3 + ((c0 == 0) ? 0 : 1)) * OH;
    int reg1 = (rc*3 + ((c0 == WWD-2) ? 2 : 1)) * OH;

    // Phase A: conv for all 32 o's into statically-indexed regs (packed int16 pair)
    int acc[OH];
    #pragma unroll
    for (int oo = 0; oo < OH; ++oo) {
        const uint64_t* q = &sq[oo*9];
        int a0 = 0, a1 = 0;
        #pragma unroll
        for (int r = 0; r < 3; ++r) {
            #pragma unroll
            for (int c = 0; c < 3; ++c) {
                uint64_t qk = q[r*3+c];
                a0 += __popcll(P[r*4+c]   ^ qk);
                a1 += __popcll(P[r*4+c+1] ^ qk);
            }
        }
        int v0 = scor[reg0 + oo] - 2*a0;
        int v1 = scor[reg1 + oo] - 2*a1;
        acc[oo] = (int)((uint32_t)(uint16_t)v0 | ((uint32_t)(uint16_t)v1 << 16));
    }

    // Phase B: pure streaming — load x, BN+res+PReLU, store
    const float2* x2 = (const float2*)x + ((size_t)n * C + obase) * (HW/2) + pr;
    float2*       o2 = (float2*)out     + ((size_t)n * C + obase) * (HW/2) + pr;
    #pragma unroll
    for (int oo = 0; oo < OH; ++oo) {
        int a = acc[oo];
        float v0 = (float)(int)(short)(a & 0xFFFF);
        float v1 = (float)(int)(short)((uint32_t)a >> 16);
        float4 t4 = tab[oo];
        float2 xv = x2[(size_t)oo * (HW/2)];
        float t0 = t4.x * v0 + t4.y + xv.x;
        float t1 = t4.x * v1 + t4.y + xv.y;
        t0 = t0 > 0.f ? t0 : t4.z * t0;
        t1 = t1 > 0.f ? t1 : t4.z * t1;
        o2[(size_t)oo * (HW/2)] = make_float2(t0 + t4.w, t1 + t4.w);
    }
}

extern "C" void kernel_launch(void* const* d_in, const int* in_sizes, int n_in,
                              void* d_out, int out_size, void* d_ws, size_t ws_size,
                              hipStream_t stream) {
    const float* x     = (const float*)d_in[0];
    const float* b0    = (const float*)d_in[1];
    const float* w     = (const float*)d_in[2];
    const float* gamma = (const float*)d_in[3];
    const float* beta  = (const float*)d_in[4];
    const float* b1    = (const float*)d_in[5];
    const float* alpha = (const float*)d_in[6];
    const float* b2    = (const float*)d_in[7];

    char* ws = (char*)d_ws;
    const size_t XPB = (size_t)NB * HW * sizeof(uint64_t);   // 3,211,264 B
    uint64_t* xp     = (uint64_t*)ws;
    uint64_t* wbits  = (uint64_t*)(ws + XPB);                // 4608 B
    u64t*     pq     = (u64t*)(ws + XPB + 4608);             // 4096 B
    float*    wscale = (float*)(ws + XPB + 4608 + 4096);     // 256 B
    int*      corrP  = (int*)(ws + XPB + 4608 + 4096 + 256); // 2304 B
    int*      ps     = (int*)(ws + XPB + 4608 + 4096 + 256 + 2304); // 2048 B

    hipLaunchKernelGGL(k_prep_pack, dim3(PACK_BLKS + 64), dim3(256), 0, stream,
                       x, b0, w, xp, wbits, wscale, corrP, ps, pq);
    hipLaunchKernelGGL(k_convstats, dim3(CONV_BLKS, NB, 2), dim3(256), 0, stream,
                       xp, wbits, corrP, ps, pq);
    hipLaunchKernelGGL(k_finish, dim3(CONV_BLKS, NB, 2), dim3(256), 0, stream,
                       xp, wbits, corrP, ps, pq, x, wscale, gamma, beta, b1, alpha, b2,
                       (float*)d_out);
}

// Round 6
// 120.856 us; speedup vs baseline: 1.2443x; 1.0453x over previous
//
#include <hip/hip_runtime.h>
#include <stdint.h>

#define C 64
#define HH 112
#define WWD 112
#define HW (HH*WWD)
#define NB 32
#define MTOT (NB*HW)
#define PPR 56          // pixel-pairs per row
#define PPI 6272        // pixel-pairs per image (HW/2)
#define PACK_BLKS 1568  // 32 images * 49 chunks of 256 pixels
#define CONV_BLKS 25    // ceil(PPI/256)
#define OH 32           // output channels per conv block (z-split in 2)
#define FL4 3136        // float4 per plane (HW/4)

typedef unsigned long long u64t;

// ---- K1: pack sign bitplane (blocks 0..1567) + weight prep (blocks 1568..1631)
//          + zero stats accumulators (block 1568, threads 64..255)
__global__ __launch_bounds__(256) void k_prep_pack(
        const float* __restrict__ x, const float* __restrict__ b0,
        const float* __restrict__ w,
        uint64_t* __restrict__ xp,
        uint64_t* __restrict__ wbits, float* __restrict__ wscale,
        int* __restrict__ corrP, int* __restrict__ ps, u64t* __restrict__ pq) {
    int bid = blockIdx.x;
    if (bid < PACK_BLKS) {
        int n = bid / 49;
        int pix = (bid % 49) * 256 + threadIdx.x;
        uint64_t p = 0;
        const float* xb = x + (size_t)n * C * HW + pix;
        #pragma unroll
        for (int c = 0; c < C; ++c) {
            float v = xb[(size_t)c * HW] + b0[c];
            p |= (uint64_t)(v > 0.f) << c;
        }
        xp[(size_t)n*HW + pix] = p;
    } else {
        int tid = threadIdx.x;
        int o = bid - PACK_BLKS;            // 0..63
        if (tid < 64) {
            int i = tid;                    // input channel
            const float* wp = w + ((size_t)o*C + i)*9;
            float s = 0.f;
            uint64_t b[9];
            #pragma unroll
            for (int k = 0; k < 9; ++k) {
                float v = wp[k];
                s += fabsf(v);
                b[k] = __ballot(v > 0.f);
            }
            #pragma unroll
            for (int off = 32; off > 0; off >>= 1) s += __shfl_down(s, off);
            if (i == 0) {
                wscale[o] = s * (1.0f/576.0f);
                int pq9[9];
                #pragma unroll
                for (int k = 0; k < 9; ++k) {
                    wbits[o*9+k] = b[k];
                    pq9[k] = __popcll(b[k]);
                }
                for (int rc = 0; rc < 3; ++rc)
                    for (int cc = 0; cc < 3; ++cc) {
                        int corr = 0;
                        for (int kr = 0; kr < 3; ++kr)
                            for (int kc = 0; kc < 3; ++kc) {
                                bool oob = (rc==0 && kr==0) || (rc==2 && kr==2) ||
                                           (cc==0 && kc==0) || (cc==2 && kc==2);
                                if (oob) corr += 64 - 2*pq9[kr*3+kc];
                            }
                        corrP[(rc*3+cc)*C + o] = 576 - corr;
                    }
            }
        } else if (bid == PACK_BLKS) {
            for (int i = tid - 64; i < C*8; i += 192) { ps[i] = 0; pq[i] = 0ull; }
        }
    }
}

// ---- K2: conv computed ONCE: int16 store into d_out planes + fused BN-stats.
__global__ __launch_bounds__(256) void k_convstats(
        const uint64_t* __restrict__ xp, const uint64_t* __restrict__ wbits,
        const int* __restrict__ corrP, int* __restrict__ ps, u64t* __restrict__ pq,
        uint32_t* __restrict__ cv) {
    __shared__ uint64_t sq[OH*9];
    __shared__ int scor[9*OH];
    __shared__ int lsw[4][OH];
    __shared__ int lqw[4][OH];
    const int obase = blockIdx.z * OH;
    for (int i = threadIdx.x; i < OH*9; i += 256) sq[i] = wbits[obase*9 + i];
    for (int i = threadIdx.x; i < 9*OH; i += 256) {
        int r = i / OH, oo = i - r*OH;
        scor[i] = corrP[r*C + obase + oo];
    }
    __syncthreads();

    int n = blockIdx.y;
    int pr = blockIdx.x * 256 + threadIdx.x;
    int act = pr < PPI;
    int prc = act ? pr : (PPI - 1);
    int row = prc / PPR;
    int j   = prc - row * PPR;
    int c0  = 2 * j;
    const uint64_t* base = xp + (size_t)n * HW;
    uint64_t P[12];
    #pragma unroll
    for (int r = 0; r < 3; ++r) {
        int rr = row + r - 1;
        bool okr = (rr >= 0) & (rr < HH);
        #pragma unroll
        for (int c = 0; c < 4; ++c) {
            int cc = c0 + c - 1;
            bool ok = okr & (cc >= 0) & (cc < WWD);
            P[r*4+c] = ok ? base[(size_t)rr * WWD + cc] : 0ull;
        }
    }
    int rc   = (row == 0) ? 0 : ((row == HH-1) ? 2 : 1);
    int reg0 = (rc*3 + ((c0 == 0) ? 0 : 1)) * OH;
    int reg1 = (rc*3 + ((c0 == WWD-2) ? 2 : 1)) * OH;
    int wid = threadIdx.x >> 6, lane = threadIdx.x & 63;

    uint32_t* op = cv + ((size_t)n * C + obase) * HW + prc;

    #pragma unroll 2
    for (int oo = 0; oo < OH; ++oo) {
        const uint64_t* q = &sq[oo*9];
        int a0 = 0, a1 = 0;
        #pragma unroll
        for (int r = 0; r < 3; ++r) {
            #pragma unroll
            for (int c = 0; c < 3; ++c) {
                uint64_t qk = q[r*3+c];
                a0 += __popcll(P[r*4+c]   ^ qk);
                a1 += __popcll(P[r*4+c+1] ^ qk);
            }
        }
        int v0 = scor[reg0 + oo] - 2*a0;
        int v1 = scor[reg1 + oo] - 2*a1;
        if (act) op[(size_t)oo * HW] =
            (uint32_t)(uint16_t)v0 | ((uint32_t)(uint16_t)v1 << 16);
        int s  = act ? (v0 + v1) : 0;
        int qq = act ? (v0*v0 + v1*v1) : 0;
        #pragma unroll
        for (int off = 1; off < 64; off <<= 1) {
            s  += __shfl_xor(s,  off);
            qq += __shfl_xor(qq, off);
        }
        if (lane == 0) { lsw[wid][oo] = s; lqw[wid][oo] = qq; }
    }
    __syncthreads();
    int t = threadIdx.x;
    int bkt = blockIdx.y & 7;
    if (t < OH) {
        int st = lsw[0][t] + lsw[1][t] + lsw[2][t] + lsw[3][t];
        atomicAdd(&ps[(obase + t)*8 + bkt], st);
    } else if (t < 2*OH) {
        int oo = t - OH;
        unsigned int qt = (unsigned)lqw[0][oo] + (unsigned)lqw[1][oo]
                        + (unsigned)lqw[2][oo] + (unsigned)lqw[3][oo];
        atomicAdd(&pq[(obase + oo)*8 + bkt], (u64t)qt);
    }
}

// ---- K3: pure streaming finish. One block per (n,o) plane; register-stage the
//          plane's int16 conv values, barrier, then stream x->out.
__global__ __launch_bounds__(256) void k_finish(
        const uint32_t* __restrict__ cv, const float* __restrict__ x,
        const int* __restrict__ ps, const u64t* __restrict__ pq,
        const float* __restrict__ wscale, const float* __restrict__ gamma,
        const float* __restrict__ beta, const float* __restrict__ b1,
        const float* __restrict__ alpha, const float* __restrict__ b2,
        float* __restrict__ out) {
    int o = blockIdx.x;   // 0..63
    int n = blockIdx.y;   // 0..31
    size_t plane = (size_t)n * C + o;

    // BN affine, uniform per thread
    int s = 0; u64t qv = 0;
    #pragma unroll
    for (int k = 0; k < 8; ++k) { s += ps[o*8+k]; qv += pq[o*8+k]; }
    const float inv = 1.0f / (float)MTOT;
    float sc   = wscale[o];
    float mean = (float)s * inv;
    float ek2  = (float)qv * inv;
    float mu   = sc * mean;
    float var  = sc*sc*ek2 - mu*mu;
    float g    = gamma[o] * rsqrtf(var + 1e-5f);
    float A    = g * sc;
    float B    = beta[o] - g*mu + b1[o];
    float al   = alpha[o];
    float bb2  = b2[o];

    // stage this plane's int16 conv data into registers (avoids in-place race)
    const uint2* cv2 = (const uint2*)cv + plane * (size_t)(HW/2);
    uint2 rbuf[13];
    #pragma unroll
    for (int k = 0; k < 13; ++k) {
        int i = threadIdx.x + k*256;
        if (i < FL4) rbuf[k] = cv2[i];
    }
    __syncthreads();

    const float4* x4 = (const float4*)x + plane * (size_t)FL4;
    float4*       o4 = (float4*)out     + plane * (size_t)FL4;
    #pragma unroll
    for (int k = 0; k < 13; ++k) {
        int i = threadIdx.x + k*256;
        if (i < FL4) {
            uint2 u = rbuf[k];
            float4 xv = x4[i], r;
            float t;
            t = A * (float)(int)(short)(u.x & 0xFFFF) + B + xv.x; t = t > 0.f ? t : al*t; r.x = t + bb2;
            t = A * (float)(int)(short)(u.x >> 16)    + B + xv.y; t = t > 0.f ? t : al*t; r.y = t + bb2;
            t = A * (float)(int)(short)(u.y & 0xFFFF) + B + xv.z; t = t > 0.f ? t : al*t; r.z = t + bb2;
            t = A * (float)(int)(short)(u.y >> 16)    + B + xv.w; t = t > 0.f ? t : al*t; r.w = t + bb2;
            o4[i] = r;
        }
    }
}

extern "C" void kernel_launch(void* const* d_in, const int* in_sizes, int n_in,
                              void* d_out, int out_size, void* d_ws, size_t ws_size,
                              hipStream_t stream) {
    const float* x     = (const float*)d_in[0];
    const float* b0    = (const float*)d_in[1];
    const float* w     = (const float*)d_in[2];
    const float* gamma = (const float*)d_in[3];
    const float* beta  = (const float*)d_in[4];
    const float* b1    = (const float*)d_in[5];
    const float* alpha = (const float*)d_in[6];
    const float* b2    = (const float*)d_in[7];

    char* ws = (char*)d_ws;
    const size_t XPB = (size_t)NB * HW * sizeof(uint64_t);   // 3,211,264 B
    uint64_t* xp     = (uint64_t*)ws;
    uint64_t* wbits  = (uint64_t*)(ws + XPB);                // 4608 B
    u64t*     pq     = (u64t*)(ws + XPB + 4608);             // 4096 B
    float*    wscale = (float*)(ws + XPB + 4608 + 4096);     // 256 B
    int*      corrP  = (int*)(ws + XPB + 4608 + 4096 + 256); // 2304 B
    int*      ps     = (int*)(ws + XPB + 4608 + 4096 + 256 + 2304); // 2048 B

    uint32_t* cv = (uint32_t*)d_out;

    hipLaunchKernelGGL(k_prep_pack, dim3(PACK_BLKS + 64), dim3(256), 0, stream,
                       x, b0, w, xp, wbits, wscale, corrP, ps, pq);
    hipLaunchKernelGGL(k_convstats, dim3(CONV_BLKS, NB, 2), dim3(256), 0, stream,
                       xp, wbits, corrP, ps, pq, cv);
    hipLaunchKernelGGL(k_finish, dim3(C, NB), dim3(256), 0, stream,
                       cv, x, ps, pq, wscale, gamma, beta, b1, alpha, b2,
                       (float*)d_out);
}